// Round 1
// baseline (1523.992 us; speedup 1.0000x reference)
//
#include <hip/hip_runtime.h>
#include <hip/hip_bf16.h>
#include <type_traits>
#include <stdint.h>

#define B_ 16
#define S_ 2048
#define H_ 1024
static constexpr float NEG_INF_F = -10000000.0f;
static constexpr float SCALE_F   = 0.03125f;   // 1/sqrt(1024)

#define BM 128
#define BN 128
#define BK 32
#define LDK 40   // BK + 8 pad: row stride 80B -> ds_read_b128 ~2-way (free)

typedef __attribute__((ext_vector_type(4))) float  f32x4;
typedef __attribute__((ext_vector_type(8))) short  bf16x8;
typedef __attribute__((ext_vector_type(4))) short  s16x4;

__device__ __forceinline__ short f2bf(float f) {
  uint32_t u = __float_as_uint(f);
  u = (u + 0x7FFFu + ((u >> 16) & 1u)) >> 16;   // RNE bf16 (inputs never NaN)
  return (short)u;
}

// Stage a 128x32 tile (row-major, leading dim ld) into LDS as bf16.
// 256 threads: thread t -> row t/2, cols [(t&1)*16, +16). 64B/thread contiguous.
template<typename T>
__device__ __forceinline__ void stage_tile(const T* __restrict__ src, int ld,
                                           short* __restrict__ lds) {
  const int t = threadIdx.x;
  const int r = t >> 1;
  const int c = (t & 1) << 4;
  const T* p = src + (size_t)r * ld + c;
  bf16x8 w0, w1;
  if constexpr (sizeof(T) == 4) {
    const f32x4* q = (const f32x4*)p;
    f32x4 u0 = q[0], u1 = q[1], u2 = q[2], u3 = q[3];
    #pragma unroll
    for (int i = 0; i < 4; ++i) {
      w0[i]     = f2bf(u0[i]);
      w0[i + 4] = f2bf(u1[i]);
      w1[i]     = f2bf(u2[i]);
      w1[i + 4] = f2bf(u3[i]);
    }
  } else {
    const bf16x8* q = (const bf16x8*)p;
    w0 = q[0];
    w1 = q[1];
  }
  *(bf16x8*)&lds[r * LDK + c]     = w0;
  *(bf16x8*)&lds[r * LDK + c + 8] = w1;
}

// B^T-layout bf16 MFMA GEMM: C[m][n] = sum_k A[m][k] * B[n][k]
// MODE 0: A f32, B f32(W), +bias, out bf16 row-major       (Q/K projection)
// MODE 1: A f32, B f32(W), +bias, out bf16 TRANSPOSED V^T  (V projection)
// MODE 2: A bf16, B bf16, out f32 = acc*scale + causal mask (scores)
// MODE 3: A f32(attn), B bf16(V^T), out f32                 (context)
template<int MODE>
__launch_bounds__(256)
__global__ void gemm_bt(const void* __restrict__ Ap, const void* __restrict__ Bp,
                        const float* __restrict__ bias, void* __restrict__ Cp,
                        int K, int lda, int ldb, int ldc,
                        long long strA, long long strB, long long strC) {
  using AT = std::conditional_t<MODE == 2, short, float>;
  using BT = std::conditional_t<(MODE <= 1), float, short>;

  __shared__ short shA[BM * LDK];
  __shared__ short shB[BN * LDK];

  const int z = blockIdx.z;
  const AT* A  = (const AT*)Ap + (size_t)z * strA;
  const BT* Bm = (const BT*)Bp + (size_t)z * strB;

  const int row0 = blockIdx.x * BM;
  const int col0 = blockIdx.y * BN;

  const int lane = threadIdx.x & 63;
  const int wid  = threadIdx.x >> 6;
  const int wm = (wid >> 1) * 64;   // 2x2 waves, 64x64 each
  const int wn = (wid & 1) * 64;
  const int lr = lane & 15;
  const int lk = (lane >> 4) << 3;

  f32x4 acc[4][4] = {};

  for (int kt = 0; kt < K; kt += BK) {
    __syncthreads();
    stage_tile<AT>(A  + (size_t)row0 * lda + kt, lda, shA);
    stage_tile<BT>(Bm + (size_t)col0 * ldb + kt, ldb, shB);
    __syncthreads();
    bf16x8 af[4], bfr[4];
    #pragma unroll
    for (int i = 0; i < 4; ++i) {
      af[i]  = *(const bf16x8*)&shA[(wm + i * 16 + lr) * LDK + lk];
      bfr[i] = *(const bf16x8*)&shB[(wn + i * 16 + lr) * LDK + lk];
    }
    #pragma unroll
    for (int i = 0; i < 4; ++i)
      #pragma unroll
      for (int j = 0; j < 4; ++j)
        acc[i][j] = __builtin_amdgcn_mfma_f32_16x16x32_bf16(af[i], bfr[j], acc[i][j], 0, 0, 0);
  }

  // C/D layout: col = lane&15, row = (lane>>4)*4 + reg
  #pragma unroll
  for (int i = 0; i < 4; ++i) {
    #pragma unroll
    for (int j = 0; j < 4; ++j) {
      const int mb = row0 + wm + i * 16 + ((lane >> 4) << 2);
      const int n  = col0 + wn + j * 16 + lr;
      f32x4 a = acc[i][j];
      if constexpr (MODE == 0) {
        short* out = (short*)Cp;
        const float bv = bias[n];
        #pragma unroll
        for (int r = 0; r < 4; ++r)
          out[(size_t)(mb + r) * ldc + n] = f2bf(a[r] + bv);
      } else if constexpr (MODE == 1) {
        const float bv = bias[n];
        const int bb = mb >> 11;          // batch  (S_=2048)
        const int ss = mb & (S_ - 1);     // seq pos, multiple of 4
        s16x4 pk;
        #pragma unroll
        for (int r = 0; r < 4; ++r) pk[r] = f2bf(a[r] + bv);
        *(s16x4*)((short*)Cp + ((size_t)bb * H_ + n) * S_ + ss) = pk;
      } else if constexpr (MODE == 2) {
        float* out = (float*)Cp + (size_t)z * strC;
        #pragma unroll
        for (int r = 0; r < 4; ++r) {
          const int m = mb + r;           // q index; n = k index
          out[(size_t)m * ldc + n] = a[r] * SCALE_F + (n >= m ? NEG_INF_F : 0.0f);
        }
      } else {
        float* out = (float*)Cp + (size_t)z * strC;
        #pragma unroll
        for (int r = 0; r < 4; ++r)
          out[(size_t)(mb + r) * ldc + n] = a[r];
      }
    }
  }
}

// Column softmax (over q axis) in place on attn (B,S,S) f32.
// Block: 256 threads = 64 columns x 4 q-strides. Grid: (S/64, B).
__launch_bounds__(256)
__global__ void softmax_col(float* __restrict__ attn) {
  const int b   = blockIdx.y;
  const int c   = threadIdx.x & 63;
  const int col = blockIdx.x * 64 + c;
  const int qo  = threadIdx.x >> 6;
  float* base = attn + (size_t)b * S_ * S_ + col;

  float m = -3.4e38f, s = 0.0f;
  for (int q = qo; q < S_; q += 4) {
    float x = base[(size_t)q * S_];
    float mn = fmaxf(m, x);
    s = s * __expf(m - mn) + __expf(x - mn);
    m = mn;
  }
  __shared__ float sm[4][64];
  __shared__ float ss[4][64];
  sm[qo][c] = m;
  ss[qo][c] = s;
  __syncthreads();
  const float M = fmaxf(fmaxf(sm[0][c], sm[1][c]), fmaxf(sm[2][c], sm[3][c]));
  const float Ssum = ss[0][c] * __expf(sm[0][c] - M) + ss[1][c] * __expf(sm[1][c] - M)
                   + ss[2][c] * __expf(sm[2][c] - M) + ss[3][c] * __expf(sm[3][c] - M);
  const float inv = 1.0f / Ssum;
  for (int q = qo; q < S_; q += 4) {
    float x = base[(size_t)q * S_];
    base[(size_t)q * S_] = __expf(x - M) * inv;
  }
}

extern "C" void kernel_launch(void* const* d_in, const int* in_sizes, int n_in,
                              void* d_out, int out_size, void* d_ws, size_t ws_size,
                              hipStream_t stream) {
  const float* queries = (const float*)d_in[0];
  const float* keys    = (const float*)d_in[1];
  const float* values  = (const float*)d_in[2];
  const float* Wq = (const float*)d_in[3];
  const float* bq = (const float*)d_in[4];
  const float* Wk = (const float*)d_in[5];
  const float* bk = (const float*)d_in[6];
  const float* Wv = (const float*)d_in[7];
  const float* bv = (const float*)d_in[8];

  float* ctx  = (float*)d_out;                       // (B,S,H) f32
  float* attn = ctx + (size_t)B_ * S_ * H_;          // (B,S,S) f32

  short* Qb = (short*)d_ws;                          // (B,S,H) bf16
  short* Kb = Qb + (size_t)B_ * S_ * H_;             // (B,S,H) bf16
  short* Vt = Kb + (size_t)B_ * S_ * H_;             // (B,H,S) bf16 (transposed)

  dim3 blk(256, 1, 1);

  // 1) Projections: M = B*S = 32768, N = H, K = H
  dim3 gproj(32768 / BM, H_ / BN, 1);   // 256 x 8
  gemm_bt<0><<<gproj, blk, 0, stream>>>(queries, Wq, bq, Qb, H_, H_, H_, H_, 0LL, 0LL, 0LL);
  gemm_bt<0><<<gproj, blk, 0, stream>>>(keys,    Wk, bk, Kb, H_, H_, H_, H_, 0LL, 0LL, 0LL);
  gemm_bt<1><<<gproj, blk, 0, stream>>>(values,  Wv, bv, Vt, H_, H_, H_, 0,  0LL, 0LL, 0LL);

  // 2) Scores + scale + causal mask -> attn region (f32)
  dim3 gsc(S_ / BM, S_ / BN, B_);       // 16 x 16 x 16
  gemm_bt<2><<<gsc, blk, 0, stream>>>(Qb, Kb, nullptr, attn, H_, H_, H_, S_,
                                      (long long)S_ * H_, (long long)S_ * H_,
                                      (long long)S_ * S_);

  // 3) Softmax over the query axis, in place
  softmax_col<<<dim3(S_ / 64, B_, 1), blk, 0, stream>>>(attn);

  // 4) context = attn @ V   (A = attn f32, B = V^T bf16)
  dim3 gctx(S_ / BM, H_ / BN, B_);      // 16 x 8 x 16
  gemm_bt<3><<<gctx, blk, 0, stream>>>(attn, Vt, nullptr, ctx, S_, S_, S_, H_,
                                       (long long)S_ * S_, (long long)H_ * S_,
                                       (long long)S_ * H_);
}

// Round 2
// 1092.258 us; speedup vs baseline: 1.3953x; 1.3953x over previous
//
#include <hip/hip_runtime.h>
#include <hip/hip_bf16.h>
#include <type_traits>
#include <stdint.h>

#define B_ 16
#define S_ 2048
#define H_ 1024
static constexpr float NEG_INF_F = -10000000.0f;
static constexpr float SCALE_F   = 0.03125f;   // 1/sqrt(1024)

#define BM 128
#define BN 128
#define BK 32
#define LDA3 40   // padded stride (shorts) for f32-source A staging (80B = 5*16B, aligned)

typedef __attribute__((ext_vector_type(4))) float  f32x4;
typedef __attribute__((ext_vector_type(8))) short  bf16x8;
typedef __attribute__((ext_vector_type(4))) short  s16x4;

__device__ __forceinline__ short f2bf(float f) {
  uint32_t u = __float_as_uint(f);
  u = (u + 0x7FFFu + ((u >> 16) & 1u)) >> 16;   // RNE bf16
  return (short)u;
}

__device__ __forceinline__ void gload16(const void* g, void* l) {
  __builtin_amdgcn_global_load_lds(
      (const __attribute__((address_space(1))) unsigned int*)g,
      (__attribute__((address_space(3))) unsigned int*)l, 16, 0, 0);
}

// Stage a 128x32 bf16 tile into linear LDS [128][32] via global_load_lds width-16.
// Wave w covers rows [w*32, w*32+32) in 2 issues; lane l -> row +(l>>2), col (l&3)*8.
__device__ __forceinline__ void stage_gl(const short* __restrict__ src, int ld,
                                         short* __restrict__ lds) {
  const int w = threadIdx.x >> 6;
  const int l = threadIdx.x & 63;
  #pragma unroll
  for (int i = 0; i < 2; ++i) {
    const int rbase = w * 32 + i * 16;
    const int r = rbase + (l >> 2);
    gload16(src + (size_t)r * ld + ((l & 3) << 3), &lds[rbase * 32]);
  }
}

// Stage a 128x32 f32 tile as bf16 into padded LDS [128][LDA3] (reg round-trip).
__device__ __forceinline__ void stage_f32(const float* __restrict__ src, int ld,
                                          short* __restrict__ lds) {
  const int t = threadIdx.x;
  const int r = t >> 1;
  const int c = (t & 1) << 4;
  const f32x4* q = (const f32x4*)(src + (size_t)r * ld + c);
  f32x4 u0 = q[0], u1 = q[1], u2 = q[2], u3 = q[3];
  bf16x8 w0, w1;
  #pragma unroll
  for (int i = 0; i < 4; ++i) {
    w0[i]     = f2bf(u0[i]);
    w0[i + 4] = f2bf(u1[i]);
    w1[i]     = f2bf(u2[i]);
    w1[i + 4] = f2bf(u3[i]);
  }
  *(bf16x8*)&lds[r * LDA3 + c]     = w0;
  *(bf16x8*)&lds[r * LDA3 + c + 8] = w1;
}

// C[m][n] = sum_k A[m][k]*B[n][k]  (B^T layout), bf16 MFMA.
// MODE 0: A bf16, B bf16(W), +bias, out bf16 row-major        (Q/K projection)
// MODE 1: A bf16, B bf16(W), +bias, out bf16 transposed (V^T) (V projection)
// MODE 2: A bf16, B bf16, out f32 = acc*scale + causal mask; skips fully-masked
//         tiles except the last tile-column (needed for k=2047 softmax)
// MODE 3: A f32(attn), B bf16(V^T), out f32; triangular K-loop (+last k-tile)
template<int MODE>
__launch_bounds__(256)
__global__ void gemm_bt(const void* __restrict__ Ap, const void* __restrict__ Bp,
                        const float* __restrict__ bias, void* __restrict__ Cp,
                        int K, int lda, int ldb, int ldc,
                        long long strA, long long strB, long long strC) {
  constexpr bool AF32 = (MODE == 3);
  constexpr int LDA_SH = AF32 ? LDA3 : 32;
  __shared__ short shA[BM * LDA_SH];
  __shared__ short shB[BN * 32];

  if constexpr (MODE == 2) {
    // tile fully masked (above diagonal) and not the last tile-column -> attn
    // there is exactly 0 after softmax; normalize pass writes the zeros.
    if (blockIdx.y > blockIdx.x && blockIdx.y != gridDim.y - 1) return;
  }

  const int z = blockIdx.z;
  const int row0 = blockIdx.x * BM;
  const int col0 = blockIdx.y * BN;
  const int lane = threadIdx.x & 63;
  const int wid  = threadIdx.x >> 6;
  const int wm = (wid >> 1) * 64;
  const int wn = (wid & 1) * 64;
  const int lr = lane & 15;
  const int lk = (lane >> 4) << 3;

  f32x4 acc[4][4] = {};

  auto do_k = [&](int kt) {
    __syncthreads();
    if constexpr (AF32) {
      const float* A = (const float*)Ap + (size_t)z * strA;
      stage_f32(A + (size_t)row0 * lda + kt, lda, shA);
    } else {
      const short* A = (const short*)Ap + (size_t)z * strA;
      stage_gl(A + (size_t)row0 * lda + kt, lda, shA);
    }
    const short* Bm = (const short*)Bp + (size_t)z * strB;
    stage_gl(Bm + (size_t)col0 * ldb + kt, ldb, shB);
    __syncthreads();   // drains vmcnt (global_load_lds) + lgkm
    bf16x8 af[4], bfr[4];
    #pragma unroll
    for (int i = 0; i < 4; ++i) {
      af[i]  = *(const bf16x8*)&shA[(wm + i * 16 + lr) * LDA_SH + lk];
      bfr[i] = *(const bf16x8*)&shB[(wn + i * 16 + lr) * 32 + lk];
    }
    #pragma unroll
    for (int i = 0; i < 4; ++i)
      #pragma unroll
      for (int j = 0; j < 4; ++j)
        acc[i][j] = __builtin_amdgcn_mfma_f32_16x16x32_bf16(af[i], bfr[j], acc[i][j], 0, 0, 0);
  };

  int kmain = K;
  if constexpr (MODE == 3) {
    int km = (blockIdx.x + 1) * BM;       // attn rows q < row0+BM have k<q nonzero
    kmain = km < K ? km : K;
  }
  for (int kt = 0; kt < kmain; kt += BK) do_k(kt);
  if constexpr (MODE == 3) {
    if (kmain < K)                         // last k-tile: dense attn column 2047
      for (int kt = K - BM; kt < K; kt += BK) do_k(kt);
  }

  // C/D layout: col = lane&15, row = (lane>>4)*4 + reg
  #pragma unroll
  for (int i = 0; i < 4; ++i) {
    #pragma unroll
    for (int j = 0; j < 4; ++j) {
      const int mb = row0 + wm + i * 16 + ((lane >> 4) << 2);
      const int n  = col0 + wn + j * 16 + lr;
      f32x4 a = acc[i][j];
      if constexpr (MODE == 0) {
        short* out = (short*)Cp;
        const float bv = bias[n];
        #pragma unroll
        for (int r = 0; r < 4; ++r)
          out[(size_t)(mb + r) * ldc + n] = f2bf(a[r] + bv);
      } else if constexpr (MODE == 1) {
        const float bv = bias[n];
        const int bb = mb >> 11;          // batch (S_=2048)
        const int ss = mb & (S_ - 1);
        s16x4 pk;
        #pragma unroll
        for (int r = 0; r < 4; ++r) pk[r] = f2bf(a[r] + bv);
        *(s16x4*)((short*)Cp + ((size_t)bb * H_ + n) * S_ + ss) = pk;
      } else if constexpr (MODE == 2) {
        float* out = (float*)Cp + (size_t)z * strC;
        #pragma unroll
        for (int r = 0; r < 4; ++r) {
          const int m = mb + r;
          out[(size_t)m * ldc + n] = a[r] * SCALE_F + (n >= m ? NEG_INF_F : 0.0f);
        }
      } else {
        float* out = (float*)Cp + (size_t)z * strC;
        #pragma unroll
        for (int r = 0; r < 4; ++r)
          out[(size_t)(mb + r) * ldc + n] = a[r];
      }
    }
  }
}

// f32 -> bf16 bulk convert (grid-stride, float4 in / short4 out)
__launch_bounds__(256)
__global__ void cvt_bf16(const float* __restrict__ src, short* __restrict__ dst, int n4) {
  int i = blockIdx.x * 256 + threadIdx.x;
  const int stride = gridDim.x * 256;
  for (; i < n4; i += stride) {
    f32x4 v = ((const f32x4*)src)[i];
    s16x4 o;
    #pragma unroll
    for (int j = 0; j < 4; ++j) o[j] = f2bf(v[j]);
    ((s16x4*)dst)[i] = o;
  }
}

// Column softmax (over q axis) in place on attn (B,S,S) f32, exploiting the
// causal structure: rows q <= k are exact zeros (underflow), written directly.
// Block: 256 thr = 8 col-groups(x4 cols, float4) x 32 q-strides. Grid (S/32, B).
__launch_bounds__(256)
__global__ void softmax_col(float* __restrict__ attn) {
  const int b  = blockIdx.y;
  const int t  = threadIdx.x;
  const int cg = t & 7;
  const int qo = t >> 3;                  // 0..31
  const int k0 = blockIdx.x * 32 + cg * 4;
  float* base = attn + (size_t)b * S_ * S_;
  const bool full = (k0 == S_ - 4);       // group holding column S-1 (all-masked col)

  int qstart;
  if (full) qstart = qo;
  else { const int s0 = k0 + 1; qstart = s0 + ((qo - s0) & 31); }

  f32x4 m4, s4;
  #pragma unroll
  for (int i = 0; i < 4; ++i) { m4[i] = -3.0e38f; s4[i] = 0.0f; }

  for (int q = qstart; q < S_; q += 32) {
    f32x4 x = *(const f32x4*)&base[(size_t)q * S_ + k0];
    #pragma unroll
    for (int i = 0; i < 4; ++i) {
      float mn = fmaxf(m4[i], x[i]);
      s4[i] = s4[i] * __expf(m4[i] - mn) + __expf(x[i] - mn);
      m4[i] = mn;
    }
  }

  __shared__ f32x4 smx[32][8];
  __shared__ f32x4 ssx[32][8];
  smx[qo][cg] = m4;
  ssx[qo][cg] = s4;
  __syncthreads();

  f32x4 M4, Sm;
  #pragma unroll
  for (int i = 0; i < 4; ++i) { M4[i] = -3.0e38f; Sm[i] = 0.0f; }
  for (int j = 0; j < 32; ++j) {
    f32x4 mm = smx[j][cg];
    #pragma unroll
    for (int i = 0; i < 4; ++i) M4[i] = fmaxf(M4[i], mm[i]);
  }
  for (int j = 0; j < 32; ++j) {
    f32x4 mm = smx[j][cg], ssv = ssx[j][cg];
    #pragma unroll
    for (int i = 0; i < 4; ++i) Sm[i] += ssv[i] * __expf(mm[i] - M4[i]);
  }
  f32x4 inv;
  #pragma unroll
  for (int i = 0; i < 4; ++i) inv[i] = 1.0f / Sm[i];

  for (int q = qo; q < S_; q += 32) {
    float* p = &base[(size_t)q * S_ + k0];
    if (full || q > k0) {
      f32x4 x = *(const f32x4*)p;
      f32x4 r;
      #pragma unroll
      for (int i = 0; i < 4; ++i) r[i] = __expf(x[i] - M4[i]) * inv[i];
      *(f32x4*)p = r;
    } else {
      f32x4 zr;
      #pragma unroll
      for (int i = 0; i < 4; ++i) zr[i] = 0.0f;
      *(f32x4*)p = zr;
    }
  }
}

extern "C" void kernel_launch(void* const* d_in, const int* in_sizes, int n_in,
                              void* d_out, int out_size, void* d_ws, size_t ws_size,
                              hipStream_t stream) {
  const float* queries = (const float*)d_in[0];
  const float* keys    = (const float*)d_in[1];
  const float* values  = (const float*)d_in[2];
  const float* Wq = (const float*)d_in[3];
  const float* bq = (const float*)d_in[4];
  const float* Wk = (const float*)d_in[5];
  const float* bk = (const float*)d_in[6];
  const float* Wv = (const float*)d_in[7];
  const float* bv = (const float*)d_in[8];

  float* ctx  = (float*)d_out;                       // (B,S,H) f32
  float* attn = ctx + (size_t)B_ * S_ * H_;          // (B,S,S) f32

  short* Qb = (short*)d_ws;                          // (B,S,H) bf16
  short* Kb = Qb + (size_t)B_ * S_ * H_;
  short* Vt = Kb + (size_t)B_ * S_ * H_;             // (B,H,S) bf16

  // Scratch inside d_out regions that are written later:
  short* Wqb = (short*)ctx;                          // 3x (H,H) bf16 in ctx region
  short* Wkb = Wqb + (size_t)H_ * H_;
  short* Wvb = Wkb + (size_t)H_ * H_;
  short* Xq = (short*)attn;                          // 3x (B,S,H) bf16 in attn region
  short* Xk = Xq + (size_t)B_ * S_ * H_;
  short* Xv = Xk + (size_t)B_ * S_ * H_;

  dim3 blk(256, 1, 1);
  const int n4 = (B_ * S_ * H_) / 4;
  const int w4 = (H_ * H_) / 4;

  // 0) bf16 conversions
  cvt_bf16<<<2048, blk, 0, stream>>>(queries, Xq, n4);
  cvt_bf16<<<2048, blk, 0, stream>>>(keys,    Xk, n4);
  cvt_bf16<<<2048, blk, 0, stream>>>(values,  Xv, n4);
  cvt_bf16<<<1024, blk, 0, stream>>>(Wq, Wqb, w4);
  cvt_bf16<<<1024, blk, 0, stream>>>(Wk, Wkb, w4);
  cvt_bf16<<<1024, blk, 0, stream>>>(Wv, Wvb, w4);

  // 1) Projections: M = 32768, N = H, K = H
  dim3 gproj(32768 / BM, H_ / BN, 1);
  gemm_bt<0><<<gproj, blk, 0, stream>>>(Xq, Wqb, bq, Qb, H_, H_, H_, H_, 0LL, 0LL, 0LL);
  gemm_bt<0><<<gproj, blk, 0, stream>>>(Xk, Wkb, bk, Kb, H_, H_, H_, H_, 0LL, 0LL, 0LL);
  gemm_bt<1><<<gproj, blk, 0, stream>>>(Xv, Wvb, bv, Vt, H_, H_, H_, 0,  0LL, 0LL, 0LL);

  // 2) Scores (+scale, +causal mask) -> attn region (triangular + last tile-col)
  dim3 gsc(S_ / BM, S_ / BN, B_);
  gemm_bt<2><<<gsc, blk, 0, stream>>>(Qb, Kb, nullptr, attn, H_, H_, H_, S_,
                                      (long long)S_ * H_, (long long)S_ * H_,
                                      (long long)S_ * S_);

  // 3) Column softmax (in place, triangular-aware)
  softmax_col<<<dim3(S_ / 32, B_, 1), blk, 0, stream>>>(attn);

  // 4) context = attn @ V  (triangular K-loop + last k-tile)
  dim3 gctx(S_ / BM, H_ / BN, B_);
  gemm_bt<3><<<gctx, blk, 0, stream>>>(attn, Vt, nullptr, ctx, S_, S_, S_, H_,
                                       (long long)S_ * S_, (long long)H_ * S_,
                                       (long long)S_ * H_);
}

// Round 3
// 1084.519 us; speedup vs baseline: 1.4052x; 1.0071x over previous
//
#include <hip/hip_runtime.h>
#include <hip/hip_bf16.h>
#include <type_traits>
#include <stdint.h>

#define B_ 16
#define S_ 2048
#define H_ 1024
static constexpr float NEG_INF_F = -10000000.0f;
static constexpr float SCALE_F   = 0.03125f;   // 1/sqrt(1024)

#define BM 128
#define BN 128
#define BK 32

typedef __attribute__((ext_vector_type(4))) float  f32x4;
typedef __attribute__((ext_vector_type(8))) short  bf16x8;
typedef __attribute__((ext_vector_type(4))) short  s16x4;

__device__ __forceinline__ short f2bf(float f) {
  uint32_t u = __float_as_uint(f);
  u = (u + 0x7FFFu + ((u >> 16) & 1u)) >> 16;   // RNE bf16
  return (short)u;
}

__device__ __forceinline__ void gload16(const void* g, void* l) {
  __builtin_amdgcn_global_load_lds(
      (const __attribute__((address_space(1))) unsigned int*)g,
      (__attribute__((address_space(3))) unsigned int*)l, 16, 0, 0);
}

// Stage a 128x32 bf16 tile into linear LDS [128][32] via global_load_lds w=16.
// Wave w covers rows [w*32, w*32+32) in 2 issues; lane l -> row +(l>>2), col (l&3)*8.
__device__ __forceinline__ void stage_gl(const short* __restrict__ src, int ld,
                                         short* __restrict__ lds) {
  const int w = threadIdx.x >> 6;
  const int l = threadIdx.x & 63;
  #pragma unroll
  for (int i = 0; i < 2; ++i) {
    const int rbase = w * 32 + i * 16;
    const int r = rbase + (l >> 2);
    gload16(src + (size_t)r * ld + ((l & 3) << 3), &lds[rbase * 32]);
  }
}

// C[m][n] = sum_k A[m][k]*B[n][k]  (B^T layout), all-bf16 MFMA, gl_lds staging.
// MODE 0: +bias, out bf16 row-major          (Q/K projection)
// MODE 1: +bias, out bf16 transposed (V^T)   (V projection)
// MODE 2: out f32 = acc*scale + causal mask; skips fully-masked tiles except
//         the last tile-column (needed for the k=2047 all-masked softmax col)
// MODE 3: out f32; triangular K-loop (+ last k-tile)     (context)
template<int MODE>
__launch_bounds__(256)
__global__ void gemm_bt(const short* __restrict__ Ap, const short* __restrict__ Bp,
                        const float* __restrict__ bias, void* __restrict__ Cp,
                        int K, int lda, int ldb, int ldc,
                        long long strA, long long strB, long long strC) {
  __shared__ short shA[BM * 32];
  __shared__ short shB[BN * 32];

  if constexpr (MODE == 2) {
    if (blockIdx.y > blockIdx.x && blockIdx.y != gridDim.y - 1) return;
  }

  const int z = blockIdx.z;
  const short* A  = Ap + (size_t)z * strA;
  const short* Bm = Bp + (size_t)z * strB;
  const int row0 = blockIdx.x * BM;
  const int col0 = blockIdx.y * BN;
  const int lane = threadIdx.x & 63;
  const int wid  = threadIdx.x >> 6;
  const int wm = (wid >> 1) * 64;
  const int wn = (wid & 1) * 64;
  const int lr = lane & 15;
  const int lk = (lane >> 4) << 3;

  f32x4 acc[4][4] = {};

  auto do_k = [&](int kt) {
    __syncthreads();
    stage_gl(A  + (size_t)row0 * lda + kt, lda, shA);
    stage_gl(Bm + (size_t)col0 * ldb + kt, ldb, shB);
    __syncthreads();
    bf16x8 af[4], bfr[4];
    #pragma unroll
    for (int i = 0; i < 4; ++i) {
      af[i]  = *(const bf16x8*)&shA[(wm + i * 16 + lr) * 32 + lk];
      bfr[i] = *(const bf16x8*)&shB[(wn + i * 16 + lr) * 32 + lk];
    }
    #pragma unroll
    for (int i = 0; i < 4; ++i)
      #pragma unroll
      for (int j = 0; j < 4; ++j)
        acc[i][j] = __builtin_amdgcn_mfma_f32_16x16x32_bf16(af[i], bfr[j], acc[i][j], 0, 0, 0);
  };

  int kmain = K;
  if constexpr (MODE == 3) {
    int km = (blockIdx.x + 1) * BM;       // rows q<row0+BM: attn nonzero only k<q
    kmain = km < K ? km : K;
  }
  for (int kt = 0; kt < kmain; kt += BK) do_k(kt);
  if constexpr (MODE == 3) {
    if (kmain < K)                         // dense attn column 2047 lives here
      for (int kt = K - BM; kt < K; kt += BK) do_k(kt);
  }

  // C/D layout: col = lane&15, row = (lane>>4)*4 + reg
  #pragma unroll
  for (int i = 0; i < 4; ++i) {
    #pragma unroll
    for (int j = 0; j < 4; ++j) {
      const int mb = row0 + wm + i * 16 + ((lane >> 4) << 2);
      const int n  = col0 + wn + j * 16 + lr;
      f32x4 a = acc[i][j];
      if constexpr (MODE == 0) {
        short* out = (short*)Cp;
        const float bv = bias[n];
        #pragma unroll
        for (int r = 0; r < 4; ++r)
          out[(size_t)(mb + r) * ldc + n] = f2bf(a[r] + bv);
      } else if constexpr (MODE == 1) {
        const float bv = bias[n];
        const int bb = mb >> 11;          // batch (S_=2048)
        const int ss = mb & (S_ - 1);
        s16x4 pk;
        #pragma unroll
        for (int r = 0; r < 4; ++r) pk[r] = f2bf(a[r] + bv);
        *(s16x4*)((short*)Cp + ((size_t)bb * H_ + n) * S_ + ss) = pk;
      } else if constexpr (MODE == 2) {
        float* out = (float*)Cp + (size_t)z * strC;
        #pragma unroll
        for (int r = 0; r < 4; ++r) {
          const int m = mb + r;
          out[(size_t)m * ldc + n] = a[r] * SCALE_F + (n >= m ? NEG_INF_F : 0.0f);
        }
      } else {
        float* out = (float*)Cp + (size_t)z * strC;
        #pragma unroll
        for (int r = 0; r < 4; ++r)
          out[(size_t)(mb + r) * ldc + n] = a[r];
      }
    }
  }
}

// All six f32->bf16 conversions in one launch. grid (2048, 4).
__launch_bounds__(256)
__global__ void cvt6(const float* __restrict__ q, const float* __restrict__ k,
                     const float* __restrict__ v, const float* __restrict__ wq,
                     const float* __restrict__ wk, const float* __restrict__ wv,
                     short* __restrict__ xq, short* __restrict__ xk,
                     short* __restrict__ xv, short* __restrict__ wqb,
                     short* __restrict__ wkb, short* __restrict__ wvb) {
  const int y = blockIdx.y;
  const int stride = gridDim.x * 256;
  if (y < 3) {
    const float* s = (y == 0) ? q : (y == 1) ? k : v;
    short* d       = (y == 0) ? xq : (y == 1) ? xk : xv;
    const int n4 = (B_ * S_ * H_) / 4;
    for (int i = blockIdx.x * 256 + threadIdx.x; i < n4; i += stride) {
      f32x4 x = ((const f32x4*)s)[i];
      s16x4 o;
      #pragma unroll
      for (int j = 0; j < 4; ++j) o[j] = f2bf(x[j]);
      ((s16x4*)d)[i] = o;
    }
  } else {
    const int w4 = (H_ * H_) / 4;          // 2^18
    for (int i = blockIdx.x * 256 + threadIdx.x; i < 3 * w4; i += stride) {
      const int wsel = i >> 18;
      const int j = i & (w4 - 1);
      const float* s = (wsel == 0) ? wq : (wsel == 1) ? wk : wv;
      short* d       = (wsel == 0) ? wqb : (wsel == 1) ? wkb : wvb;
      f32x4 x = ((const f32x4*)s)[j];
      s16x4 o;
      #pragma unroll
      for (int jj = 0; jj < 4; ++jj) o[jj] = f2bf(x[jj]);
      ((s16x4*)d)[j] = o;
    }
  }
}

// Column softmax (over q axis) in place on attn (B,S,S) f32; also writes a bf16
// copy for the context GEMM. Rows q<=k are exact zeros (written, not computed).
// Block: 256 thr = 8 col-groups(x4 cols, float4) x 32 q-strides. Grid (S/32, B).
__launch_bounds__(256)
__global__ void softmax_col(float* __restrict__ attn, short* __restrict__ attn_b) {
  const int b  = blockIdx.y;
  const int t  = threadIdx.x;
  const int cg = t & 7;
  const int qo = t >> 3;                  // 0..31
  const int k0 = blockIdx.x * 32 + cg * 4;
  float* base = attn + (size_t)b * S_ * S_;
  short* bb   = attn_b + (size_t)b * S_ * S_;
  const bool full = (k0 == S_ - 4);       // group holding the all-masked col S-1

  int qstart;
  if (full) qstart = qo;
  else { const int s0 = k0 + 1; qstart = s0 + ((qo - s0) & 31); }

  f32x4 m4, s4;
  #pragma unroll
  for (int i = 0; i < 4; ++i) { m4[i] = -3.0e38f; s4[i] = 0.0f; }

  for (int q = qstart; q < S_; q += 32) {
    f32x4 x = *(const f32x4*)&base[(size_t)q * S_ + k0];
    #pragma unroll
    for (int i = 0; i < 4; ++i) {
      float mn = fmaxf(m4[i], x[i]);
      s4[i] = s4[i] * __expf(m4[i] - mn) + __expf(x[i] - mn);
      m4[i] = mn;
    }
  }

  __shared__ f32x4 smx[32][8];
  __shared__ f32x4 ssx[32][8];
  smx[qo][cg] = m4;
  ssx[qo][cg] = s4;
  __syncthreads();

  f32x4 M4, Sm;
  #pragma unroll
  for (int i = 0; i < 4; ++i) { M4[i] = -3.0e38f; Sm[i] = 0.0f; }
  for (int j = 0; j < 32; ++j) {
    f32x4 mm = smx[j][cg];
    #pragma unroll
    for (int i = 0; i < 4; ++i) M4[i] = fmaxf(M4[i], mm[i]);
  }
  for (int j = 0; j < 32; ++j) {
    f32x4 mm = smx[j][cg], ssv = ssx[j][cg];
    #pragma unroll
    for (int i = 0; i < 4; ++i) Sm[i] += ssv[i] * __expf(mm[i] - M4[i]);
  }
  f32x4 inv;
  #pragma unroll
  for (int i = 0; i < 4; ++i) inv[i] = 1.0f / Sm[i];

  for (int q = qo; q < S_; q += 32) {
    const size_t off = (size_t)q * S_ + k0;
    if (full || q > k0) {
      f32x4 x = *(const f32x4*)&base[off];
      f32x4 r;
      s16x4 rb;
      #pragma unroll
      for (int i = 0; i < 4; ++i) { r[i] = __expf(x[i] - M4[i]) * inv[i]; rb[i] = f2bf(r[i]); }
      *(f32x4*)&base[off] = r;
      *(s16x4*)&bb[off]   = rb;
    } else {
      f32x4 zr;
      s16x4 zb;
      #pragma unroll
      for (int i = 0; i < 4; ++i) { zr[i] = 0.0f; zb[i] = 0; }
      *(f32x4*)&base[off] = zr;
      *(s16x4*)&bb[off]   = zb;
    }
  }
}

extern "C" void kernel_launch(void* const* d_in, const int* in_sizes, int n_in,
                              void* d_out, int out_size, void* d_ws, size_t ws_size,
                              hipStream_t stream) {
  const float* queries = (const float*)d_in[0];
  const float* keys    = (const float*)d_in[1];
  const float* values  = (const float*)d_in[2];
  const float* Wq = (const float*)d_in[3];
  const float* bq = (const float*)d_in[4];
  const float* Wk = (const float*)d_in[5];
  const float* bk = (const float*)d_in[6];
  const float* Wv = (const float*)d_in[7];
  const float* bv = (const float*)d_in[8];

  float* ctx  = (float*)d_out;                       // (B,S,H) f32
  float* attn = ctx + (size_t)B_ * S_ * H_;          // (B,S,S) f32

  short* Qb = (short*)d_ws;                          // (B,S,H) bf16
  short* Kb = Qb + (size_t)B_ * S_ * H_;
  short* Vt = Kb + (size_t)B_ * S_ * H_;             // (B,H,S) bf16
  short* attn_b = Qb;                                // (B,S,S) bf16 reuses Qb+Kb
                                                     // (dead after scores GEMM)

  // bf16 input/weight scratch inside d_out regions written later:
  short* Wqb = (short*)ctx;                          // 3x (H,H) bf16 in ctx region
  short* Wkb = Wqb + (size_t)H_ * H_;
  short* Wvb = Wkb + (size_t)H_ * H_;
  short* Xq = (short*)attn;                          // 3x (B,S,H) bf16 in attn region
  short* Xk = Xq + (size_t)B_ * S_ * H_;
  short* Xv = Xk + (size_t)B_ * S_ * H_;

  dim3 blk(256, 1, 1);

  // 0) all f32->bf16 conversions, one launch
  cvt6<<<dim3(2048, 4, 1), blk, 0, stream>>>(queries, keys, values, Wq, Wk, Wv,
                                             Xq, Xk, Xv, Wqb, Wkb, Wvb);

  // 1) Projections: M = 32768, N = H, K = H
  dim3 gproj(32768 / BM, H_ / BN, 1);
  gemm_bt<0><<<gproj, blk, 0, stream>>>(Xq, Wqb, bq, Qb, H_, H_, H_, H_, 0LL, 0LL, 0LL);
  gemm_bt<0><<<gproj, blk, 0, stream>>>(Xk, Wkb, bk, Kb, H_, H_, H_, H_, 0LL, 0LL, 0LL);
  gemm_bt<1><<<gproj, blk, 0, stream>>>(Xv, Wvb, bv, Vt, H_, H_, H_, 0,  0LL, 0LL, 0LL);

  // 2) Scores (+scale, +causal mask) -> attn region (triangular + last tile-col)
  dim3 gsc(S_ / BM, S_ / BN, B_);
  gemm_bt<2><<<gsc, blk, 0, stream>>>(Qb, Kb, nullptr, attn, H_, H_, H_, S_,
                                      (long long)S_ * H_, (long long)S_ * H_,
                                      (long long)S_ * S_);

  // 3) Column softmax in place + bf16 copy into ws (overwrites Qb/Kb)
  softmax_col<<<dim3(S_ / 32, B_, 1), blk, 0, stream>>>(attn, attn_b);

  // 4) context = attn_b @ V^T (all bf16, triangular K-loop + last k-tile)
  dim3 gctx(S_ / BM, H_ / BN, B_);
  gemm_bt<3><<<gctx, blk, 0, stream>>>(attn_b, Vt, nullptr, ctx, S_, S_, S_, H_,
                                       (long long)S_ * S_, (long long)H_ * S_,
                                       (long long)S_ * H_);
}

// Round 4
// 1044.468 us; speedup vs baseline: 1.4591x; 1.0383x over previous
//
#include <hip/hip_runtime.h>
#include <hip/hip_bf16.h>
#include <type_traits>
#include <stdint.h>

#define B_ 16
#define S_ 2048
#define H_ 1024
static constexpr float NEG_INF_F = -10000000.0f;
static constexpr float SCALE_F   = 0.03125f;   // 1/sqrt(1024)

#define BM 128
#define BN 128
#define BK 32

typedef __attribute__((ext_vector_type(4))) float  f32x4;
typedef __attribute__((ext_vector_type(8))) short  bf16x8;
typedef __attribute__((ext_vector_type(4))) short  s16x4;

__device__ __forceinline__ short f2bf(float f) {
  uint32_t u = __float_as_uint(f);
  u = (u + 0x7FFFu + ((u >> 16) & 1u)) >> 16;   // RNE bf16
  return (short)u;
}

__device__ __forceinline__ void gload16(const void* g, void* l) {
  __builtin_amdgcn_global_load_lds(
      (const __attribute__((address_space(1))) unsigned int*)g,
      (__attribute__((address_space(3))) unsigned int*)l, 16, 0, 0);
}

// Stage a 128x32 bf16 tile into linear LDS [128][32] via global_load_lds w=16.
// Wave w covers rows [w*32, w*32+32) in 2 issues; lane l -> row +(l>>2), col (l&3)*8.
__device__ __forceinline__ void stage_gl(const short* __restrict__ src, int ld,
                                         short* __restrict__ lds) {
  const int w = threadIdx.x >> 6;
  const int l = threadIdx.x & 63;
  #pragma unroll
  for (int i = 0; i < 2; ++i) {
    const int rbase = w * 32 + i * 16;
    const int r = rbase + (l >> 2);
    gload16(src + (size_t)r * ld + ((l & 3) << 3), &lds[rbase * 32]);
  }
}

// C[m][n] = sum_k A[m][k]*B[n][k]  (B^T layout), all-bf16 MFMA, gl_lds staging,
// double-buffered 2-phase K-loop (one barrier per K-step, prefetch overlapped).
// MODE 0: +bias, out bf16 row-major          (Q/K projection)   [row=blockIdx.y]
// MODE 1: +bias, out bf16 transposed (V^T)   (V projection)     [row=blockIdx.y]
// MODE 2: out f32 = acc*scale + causal mask; skips fully-masked tiles except
//         the last tile-column (needed for the k=2047 all-masked softmax col)
// MODE 3: out f32; triangular K-loop (+ last k-tile)            (context)
template<int MODE>
__launch_bounds__(256)
__global__ void gemm_bt(const short* __restrict__ Ap, const short* __restrict__ Bp,
                        const float* __restrict__ bias, void* __restrict__ Cp,
                        int K, int lda, int ldb, int ldc,
                        long long strA, long long strB, long long strC) {
  __shared__ short shA[2][BM * 32];
  __shared__ short shB[2][BN * 32];

  if constexpr (MODE == 2) {
    if (blockIdx.y > blockIdx.x && blockIdx.y != gridDim.y - 1) return;
  }

  const int z = blockIdx.z;
  const short* A  = Ap + (size_t)z * strA;
  const short* Bm = Bp + (size_t)z * strB;
  const int row0 = (MODE <= 1 ? blockIdx.y : blockIdx.x) * BM;
  const int col0 = (MODE <= 1 ? blockIdx.x : blockIdx.y) * BN;
  const int lane = threadIdx.x & 63;
  const int wid  = threadIdx.x >> 6;
  const int wm = (wid >> 1) * 64;
  const int wn = (wid & 1) * 64;
  const int lr = lane & 15;
  const int lk = (lane >> 4) << 3;

  f32x4 acc[4][4] = {};

  // K-tile schedule (handles MODE 3's triangular + last-tile segments)
  int kmain = K;
  if constexpr (MODE == 3) {
    int km = (blockIdx.x + 1) * BM;       // rows q<row0+BM: attn nonzero only k<q
    kmain = km < K ? km : K;
  }
  const int ntm = kmain / BK;
  const int nt  = ntm + ((MODE == 3 && kmain < K) ? (BM / BK) : 0);
  auto kt_of = [&](int i) -> int {
    if (i < ntm) return i * BK;
    return K - BM + (i - ntm) * BK;       // dense attn column 2047 segment
  };

  auto stage = [&](int buf, int kt) {
    stage_gl(A  + (size_t)row0 * lda + kt, lda, shA[buf]);
    stage_gl(Bm + (size_t)col0 * ldb + kt, ldb, shB[buf]);
  };
  auto compute = [&](int buf) {
    bf16x8 af[4], bfr[4];
    #pragma unroll
    for (int i = 0; i < 4; ++i) {
      af[i]  = *(const bf16x8*)&shA[buf][(wm + i * 16 + lr) * 32 + lk];
      bfr[i] = *(const bf16x8*)&shB[buf][(wn + i * 16 + lr) * 32 + lk];
    }
    #pragma unroll
    for (int i = 0; i < 4; ++i)
      #pragma unroll
      for (int j = 0; j < 4; ++j)
        acc[i][j] = __builtin_amdgcn_mfma_f32_16x16x32_bf16(af[i], bfr[j], acc[i][j], 0, 0, 0);
  };

  // prologue
  stage(0, kt_of(0));
  __syncthreads();                        // vmcnt(0)+lgkmcnt(0)+barrier
  int cur = 0;
  for (int i = 0; i < nt; ++i) {
    if (i + 1 < nt) stage(cur ^ 1, kt_of(i + 1));   // issue next-tile loads first
    compute(cur);                                   // ds_read + MFMA on current
    __syncthreads();                                // drain + publish next tile
    cur ^= 1;
  }

  // C/D layout: col = lane&15, row = (lane>>4)*4 + reg
  #pragma unroll
  for (int i = 0; i < 4; ++i) {
    #pragma unroll
    for (int j = 0; j < 4; ++j) {
      const int mb = row0 + wm + i * 16 + ((lane >> 4) << 2);
      const int n  = col0 + wn + j * 16 + lr;
      f32x4 a = acc[i][j];
      if constexpr (MODE == 0) {
        short* out = (short*)Cp;
        const float bv = bias[n];
        #pragma unroll
        for (int r = 0; r < 4; ++r)
          out[(size_t)(mb + r) * ldc + n] = f2bf(a[r] + bv);
      } else if constexpr (MODE == 1) {
        const float bv = bias[n];
        const int bb = mb >> 11;          // batch (S_=2048)
        const int ss = mb & (S_ - 1);
        s16x4 pk;
        #pragma unroll
        for (int r = 0; r < 4; ++r) pk[r] = f2bf(a[r] + bv);
        *(s16x4*)((short*)Cp + ((size_t)bb * H_ + n) * S_ + ss) = pk;
      } else if constexpr (MODE == 2) {
        float* out = (float*)Cp + (size_t)z * strC;
        #pragma unroll
        for (int r = 0; r < 4; ++r) {
          const int m = mb + r;
          out[(size_t)m * ldc + n] = a[r] * SCALE_F + (n >= m ? NEG_INF_F : 0.0f);
        }
      } else {
        float* out = (float*)Cp + (size_t)z * strC;
        #pragma unroll
        for (int r = 0; r < 4; ++r)
          out[(size_t)(mb + r) * ldc + n] = a[r];
      }
    }
  }
}

// All six f32->bf16 conversions in one launch. grid (2048, 4).
__launch_bounds__(256)
__global__ void cvt6(const float* __restrict__ q, const float* __restrict__ k,
                     const float* __restrict__ v, const float* __restrict__ wq,
                     const float* __restrict__ wk, const float* __restrict__ wv,
                     short* __restrict__ xq, short* __restrict__ xk,
                     short* __restrict__ xv, short* __restrict__ wqb,
                     short* __restrict__ wkb, short* __restrict__ wvb) {
  const int y = blockIdx.y;
  const int stride = gridDim.x * 256;
  if (y < 3) {
    const float* s = (y == 0) ? q : (y == 1) ? k : v;
    short* d       = (y == 0) ? xq : (y == 1) ? xk : xv;
    const int n4 = (B_ * S_ * H_) / 4;
    for (int i = blockIdx.x * 256 + threadIdx.x; i < n4; i += stride) {
      f32x4 x = ((const f32x4*)s)[i];
      s16x4 o;
      #pragma unroll
      for (int j = 0; j < 4; ++j) o[j] = f2bf(x[j]);
      ((s16x4*)d)[i] = o;
    }
  } else {
    const int w4 = (H_ * H_) / 4;          // 2^18
    for (int i = blockIdx.x * 256 + threadIdx.x; i < 3 * w4; i += stride) {
      const int wsel = i >> 18;
      const int j = i & (w4 - 1);
      const float* s = (wsel == 0) ? wq : (wsel == 1) ? wk : wv;
      short* d       = (wsel == 0) ? wqb : (wsel == 1) ? wkb : wvb;
      f32x4 x = ((const f32x4*)s)[j];
      s16x4 o;
      #pragma unroll
      for (int jj = 0; jj < 4; ++jj) o[jj] = f2bf(x[jj]);
      ((s16x4*)d)[j] = o;
    }
  }
}

// Column softmax (over q axis) in place on attn (B,S,S) f32; also writes a bf16
// copy for the context GEMM. Rows q<=k are exact zeros (written, not computed).
// Block: 256 thr = 8 col-groups(x4 cols, float4) x 32 q-strides. Grid (S/32, B).
__launch_bounds__(256)
__global__ void softmax_col(float* __restrict__ attn, short* __restrict__ attn_b) {
  const int b  = blockIdx.y;
  const int t  = threadIdx.x;
  const int cg = t & 7;
  const int qo = t >> 3;                  // 0..31
  const int k0 = blockIdx.x * 32 + cg * 4;
  float* base = attn + (size_t)b * S_ * S_;
  short* bb   = attn_b + (size_t)b * S_ * S_;
  const bool full = (k0 == S_ - 4);       // group holding the all-masked col S-1

  int qstart;
  if (full) qstart = qo;
  else { const int s0 = k0 + 1; qstart = s0 + ((qo - s0) & 31); }

  f32x4 m4, s4;
  #pragma unroll
  for (int i = 0; i < 4; ++i) { m4[i] = -3.0e38f; s4[i] = 0.0f; }

  for (int q = qstart; q < S_; q += 32) {
    f32x4 x = *(const f32x4*)&base[(size_t)q * S_ + k0];
    #pragma unroll
    for (int i = 0; i < 4; ++i) {
      float mn = fmaxf(m4[i], x[i]);
      s4[i] = s4[i] * __expf(m4[i] - mn) + __expf(x[i] - mn);
      m4[i] = mn;
    }
  }

  __shared__ f32x4 smx[32][8];
  __shared__ f32x4 ssx[32][8];
  smx[qo][cg] = m4;
  ssx[qo][cg] = s4;
  __syncthreads();

  f32x4 M4, Sm;
  #pragma unroll
  for (int i = 0; i < 4; ++i) { M4[i] = -3.0e38f; Sm[i] = 0.0f; }
  for (int j = 0; j < 32; ++j) {
    f32x4 mm = smx[j][cg];
    #pragma unroll
    for (int i = 0; i < 4; ++i) M4[i] = fmaxf(M4[i], mm[i]);
  }
  for (int j = 0; j < 32; ++j) {
    f32x4 mm = smx[j][cg], ssv = ssx[j][cg];
    #pragma unroll
    for (int i = 0; i < 4; ++i) Sm[i] += ssv[i] * __expf(mm[i] - M4[i]);
  }
  f32x4 inv;
  #pragma unroll
  for (int i = 0; i < 4; ++i) inv[i] = 1.0f / Sm[i];

  for (int q = qo; q < S_; q += 32) {
    const size_t off = (size_t)q * S_ + k0;
    if (full || q > k0) {
      f32x4 x = *(const f32x4*)&base[off];
      f32x4 r;
      s16x4 rb;
      #pragma unroll
      for (int i = 0; i < 4; ++i) { r[i] = __expf(x[i] - M4[i]) * inv[i]; rb[i] = f2bf(r[i]); }
      *(f32x4*)&base[off] = r;
      *(s16x4*)&bb[off]   = rb;
    } else {
      f32x4 zr;
      s16x4 zb;
      #pragma unroll
      for (int i = 0; i < 4; ++i) { zr[i] = 0.0f; zb[i] = 0; }
      *(f32x4*)&base[off] = zr;
      *(s16x4*)&bb[off]   = zb;
    }
  }
}

extern "C" void kernel_launch(void* const* d_in, const int* in_sizes, int n_in,
                              void* d_out, int out_size, void* d_ws, size_t ws_size,
                              hipStream_t stream) {
  const float* queries = (const float*)d_in[0];
  const float* keys    = (const float*)d_in[1];
  const float* values  = (const float*)d_in[2];
  const float* Wq = (const float*)d_in[3];
  const float* bq = (const float*)d_in[4];
  const float* Wk = (const float*)d_in[5];
  const float* bk = (const float*)d_in[6];
  const float* Wv = (const float*)d_in[7];
  const float* bv = (const float*)d_in[8];

  float* ctx  = (float*)d_out;                       // (B,S,H) f32
  float* attn = ctx + (size_t)B_ * S_ * H_;          // (B,S,S) f32

  short* Qb = (short*)d_ws;                          // (B,S,H) bf16
  short* Kb = Qb + (size_t)B_ * S_ * H_;
  short* Vt = Kb + (size_t)B_ * S_ * H_;             // (B,H,S) bf16
  short* attn_b = Qb;                                // (B,S,S) bf16 reuses Qb+Kb
                                                     // (dead after scores GEMM)

  // bf16 input/weight scratch inside d_out regions written later:
  short* Wqb = (short*)ctx;                          // 3x (H,H) bf16 in ctx region
  short* Wkb = Wqb + (size_t)H_ * H_;
  short* Wvb = Wkb + (size_t)H_ * H_;
  short* Xq = (short*)attn;                          // 3x (B,S,H) bf16 in attn region
  short* Xk = Xq + (size_t)B_ * S_ * H_;
  short* Xv = Xk + (size_t)B_ * S_ * H_;

  dim3 blk(256, 1, 1);

  // 0) all f32->bf16 conversions, one launch
  cvt6<<<dim3(2048, 4, 1), blk, 0, stream>>>(queries, keys, values, Wq, Wk, Wv,
                                             Xq, Xk, Xv, Wqb, Wkb, Wvb);

  // 1) Projections: M = 32768, N = H, K = H  (x=col so A row-panel reused in L2)
  dim3 gproj(H_ / BN, 32768 / BM, 1);   // 8 x 256
  gemm_bt<0><<<gproj, blk, 0, stream>>>(Xq, Wqb, bq, Qb, H_, H_, H_, H_, 0LL, 0LL, 0LL);
  gemm_bt<0><<<gproj, blk, 0, stream>>>(Xk, Wkb, bk, Kb, H_, H_, H_, H_, 0LL, 0LL, 0LL);
  gemm_bt<1><<<gproj, blk, 0, stream>>>(Xv, Wvb, bv, Vt, H_, H_, H_, 0,  0LL, 0LL, 0LL);

  // 2) Scores (+scale, +causal mask) -> attn region (triangular + last tile-col)
  dim3 gsc(S_ / BM, S_ / BN, B_);
  gemm_bt<2><<<gsc, blk, 0, stream>>>(Qb, Kb, nullptr, attn, H_, H_, H_, S_,
                                      (long long)S_ * H_, (long long)S_ * H_,
                                      (long long)S_ * S_);

  // 3) Column softmax in place + bf16 copy into ws (overwrites Qb/Kb)
  softmax_col<<<dim3(S_ / 32, B_, 1), blk, 0, stream>>>(attn, attn_b);

  // 4) context = attn_b @ V^T (all bf16, triangular K-loop + last k-tile)
  dim3 gctx(S_ / BM, H_ / BN, B_);
  gemm_bt<3><<<gctx, blk, 0, stream>>>(attn_b, Vt, nullptr, ctx, S_, S_, S_, H_,
                                       (long long)S_ * S_, (long long)H_ * S_,
                                       (long long)S_ * H_);
}